// Round 4
// baseline (879.354 us; speedup 1.0000x reference)
//
#include <hip/hip_runtime.h>
#include <stdint.h>

typedef uint32_t u32; typedef uint64_t u64;
typedef unsigned long long ull;

#define A_TOTAL 242991
#define NLVL 5
#define BATCHN 4
#define M_TOT 4741          // 1000*4 + 741
#define M_PAD 4800          // 75 * 64
#define NW 75               // mask words per row (ceil(4741/64))
#define POSTN 1000
#define CAP 4096            // candidate buffer per (batch,level)
#define IMG_W 1216.0f
#define IMG_H 800.0f
#define BBOX_CLIP 4.135166556742356f
#define NMS_T 0.7f
#define MIN_SZ 1e-3f
#define INVALID_HI 0x007FFFFFu   // sortable-u32 of -inf

// monotone float->u32 transform (order-preserving; larger float => larger key)
__device__ __forceinline__ u32 fkey(float f) {
    u32 b = __float_as_uint(f);
    return (b & 0x80000000u) ? ~b : (b | 0x80000000u);
}
__device__ __forceinline__ int level_of(int x) {
    return (x < 182400) ? 0 : (x < 228000) ? 1 : (x < 239400) ? 2 : (x < 242250) ? 3 : 4;
}

// ---------------- 1. histogram of top-16 bits of sortable objectness, per (b,level)
__global__ void k_hist(const float* __restrict__ obj, u32* __restrict__ hist) {
    int x = blockIdx.x * blockDim.x + threadIdx.x;
    int b = blockIdx.y;
    if (x >= A_TOTAL) return;
    u32 u = fkey(obj[(size_t)b * A_TOTAL + x]);
    int lvl = level_of(x);
    atomicAdd(&hist[((size_t)(b * NLVL + lvl) << 16) + (u >> 16)], 1u);
}

// ---------------- 2. find per-(b,level) boundary bin B s.t. count(bin >= B) >= k
__global__ __launch_bounds__(256) void k_thresh(const u32* __restrict__ hist, u32* __restrict__ binB) {
    int g = blockIdx.x; int lvl = g % NLVL;
    u32 k = (lvl < 4) ? 1000u : 741u;
    __shared__ u32 s[256];
    const u32* h = hist + ((size_t)g << 16);
    int t = threadIdx.x;
    u32 sum = 0;
    for (int bin = t * 256; bin < t * 256 + 256; ++bin) sum += h[bin];
    s[t] = sum;
    __syncthreads();
    if (t == 0) {
        u32 cum = 0; u32 B = 0;
        for (int c = 255; c >= 0; --c) {
            if (cum + s[c] >= k) {
                for (int bin = c * 256 + 255; bin >= c * 256; --bin) {
                    cum += h[bin];
                    if (cum >= k) { B = (u32)bin; break; }
                }
                break;
            }
            cum += s[c];
        }
        binB[g] = B;
    }
}

// ---------------- 3. compact candidates (bin >= B) with exact 64-bit key (value, ~idx)
__global__ void k_compact(const float* __restrict__ obj, const u32* __restrict__ binB,
                          u32* __restrict__ cnt, u64* __restrict__ cand) {
    int x = blockIdx.x * blockDim.x + threadIdx.x;
    int b = blockIdx.y;
    if (x >= A_TOTAL) return;
    u32 u = fkey(obj[(size_t)b * A_TOTAL + x]);
    int lvl = level_of(x);
    int g = b * NLVL + lvl;
    if ((u >> 16) >= binB[g]) {
        u32 slot = atomicAdd(&cnt[g], 1u);
        if (slot < CAP) cand[(size_t)g * CAP + slot] = ((u64)u << 32) | (u32)(~(u32)x);
    }
}

// ---------------- 4. per-(b,level) exact top-k by bitonic sort (descending); ranks match lax.top_k
__global__ __launch_bounds__(1024) void k_sortlvl(const u32* __restrict__ cnt, const u64* __restrict__ cand,
                                                  u64* __restrict__ selk) {
    __shared__ u64 buf[CAP];   // 32 KB
    int g = blockIdx.x; int b = g / NLVL; int lvl = g % NLVL;
    int n = min((int)cnt[g], CAP);
    for (int i = threadIdx.x; i < CAP; i += 1024) buf[i] = (i < n) ? cand[(size_t)g * CAP + i] : 0ull;
    __syncthreads();
    for (int k = 2; k <= CAP; k <<= 1)
        for (int j = k >> 1; j > 0; j >>= 1) {
            for (int t = threadIdx.x; t < CAP / 2; t += 1024) {
                int i = ((t & ~(j - 1)) << 1) | (t & (j - 1));
                int ix = i | j;
                u64 a = buf[i], c = buf[ix];
                bool dirup = ((i & k) != 0);           // flipped => overall descending
                bool sw = dirup ? (a > c) : (a < c);
                if (sw) { buf[i] = c; buf[ix] = a; }
            }
            __syncthreads();
        }
    int kk = (lvl < 4) ? 1000 : 741;
    int off = lvl * 1000;
    for (int r = threadIdx.x; r < kk; r += 1024)
        selk[(size_t)b * M_PAD + off + r] = buf[r];
}

// ---------------- 5. decode + clip + valid + sigmoid, build global sort key, per-batch max
// FP exactness: sigmoid = 1/(1+exp(-x)) matches XLA's LogisticExpander
// (div(1, add(1, exp(neg x))) with __ocml_exp_f32 + IEEE fdiv — same as hip expf + '/').
// All mul/add pinned un-contracted to match XLA's separate-HLO evaluation.
__global__ void k_decode(const u64* __restrict__ selk, const float* __restrict__ deltas,
                         const float* __restrict__ anchors, u64* __restrict__ skeyin,
                         float4* __restrict__ boxes, u32* __restrict__ maxbox) {
    int p = blockIdx.x * blockDim.x + threadIdx.x;
    int b = blockIdx.y;
    float lmax = 0.0f;
    if (p < M_TOT) {
        u64 key = selk[(size_t)b * M_PAD + p];
        u32 u = (u32)(key >> 32);
        u32 gidx = ~(u32)key;
        u32 ob = (u & 0x80000000u) ? (u & 0x7FFFFFFFu) : ~u;   // inverse of fkey
        float o = __uint_as_float(ob);
        float score = 1.0f / (1.0f + expf(-o));
        float4 a4 = reinterpret_cast<const float4*>(anchors)[gidx];
        float4 d4 = reinterpret_cast<const float4*>(deltas)[(size_t)b * A_TOTAL + gidx];
        float w  = __fsub_rn(a4.z, a4.x);
        float h  = __fsub_rn(a4.w, a4.y);
        float cx = __fadd_rn(a4.x, __fmul_rn(0.5f, w));
        float cy = __fadd_rn(a4.y, __fmul_rn(0.5f, h));
        float dw = fminf(d4.z, BBOX_CLIP), dh = fminf(d4.w, BBOX_CLIP);
        float pcx = __fadd_rn(__fmul_rn(d4.x, w), cx);
        float pcy = __fadd_rn(__fmul_rn(d4.y, h), cy);
        float pw = __fmul_rn(expf(dw), w);
        float ph = __fmul_rn(expf(dh), h);
        float x1 = __fsub_rn(pcx, __fmul_rn(0.5f, pw));
        float y1 = __fsub_rn(pcy, __fmul_rn(0.5f, ph));
        float x2 = __fadd_rn(pcx, __fmul_rn(0.5f, pw));
        float y2 = __fadd_rn(pcy, __fmul_rn(0.5f, ph));
        x1 = fminf(fmaxf(x1, 0.f), IMG_W); x2 = fminf(fmaxf(x2, 0.f), IMG_W);
        y1 = fminf(fmaxf(y1, 0.f), IMG_H); y2 = fminf(fmaxf(y2, 0.f), IMG_H);
        bool valid = (__fsub_rn(x2, x1) >= MIN_SZ) && (__fsub_rn(y2, y1) >= MIN_SZ);
        float masked = valid ? score : -INFINITY;
        skeyin[(size_t)b * M_PAD + p] = ((u64)fkey(masked) << 32) | (u32)(0xFFFFFFFFu - (u32)p);
        boxes[(size_t)b * M_PAD + p] = make_float4(x1, y1, x2, y2);
        lmax = fmaxf(fmaxf(x1, y1), fmaxf(x2, y2));
    }
    // wave-reduce max, one atomic per wave (all coords >= 0 so int-compare == float-compare)
    for (int o = 32; o; o >>= 1) lmax = fmaxf(lmax, __shfl_xor(lmax, o));
    if ((threadIdx.x & 63) == 0) atomicMax((int*)&maxbox[b], __float_as_int(lmax));
}

// ---------------- 6. per-batch global sort (8192 bitonic in LDS) + shifted boxes/areas
__global__ __launch_bounds__(1024) void k_sortbatch(const u64* __restrict__ skeyin, u64* __restrict__ sortedk,
                                                    const float4* __restrict__ boxes, const u32* __restrict__ maxbox,
                                                    float4* __restrict__ sbox, float* __restrict__ sarea) {
    __shared__ u64 buf[8192];   // 64 KB
    int b = blockIdx.x;
    for (int i = threadIdx.x; i < 8192; i += 1024)
        buf[i] = (i < M_TOT) ? skeyin[(size_t)b * M_PAD + i] : 0ull;
    __syncthreads();
    for (int k = 2; k <= 8192; k <<= 1)
        for (int j = k >> 1; j > 0; j >>= 1) {
            for (int t = threadIdx.x; t < 4096; t += 1024) {
                int i = ((t & ~(j - 1)) << 1) | (t & (j - 1));
                int ix = i | j;
                u64 a = buf[i], c = buf[ix];
                bool dirup = ((i & k) != 0);
                bool sw = dirup ? (a > c) : (a < c);
                if (sw) { buf[i] = c; buf[ix] = a; }
            }
            __syncthreads();
        }
    float shiftbase = __fadd_rn(__uint_as_float(maxbox[b]), 1.0f);   // jnp.max(boxes) + 1.0
    for (int i = threadIdx.x; i < M_TOT; i += 1024) {
        u64 key = buf[i];
        sortedk[(size_t)b * M_PAD + i] = key;
        u32 p = 0xFFFFFFFFu - (u32)key;
        float4 bx = boxes[(size_t)b * M_PAD + p];
        int lvl = (int)(p / 1000u);
        float sh = __fmul_rn((float)lvl, shiftbase);                 // levels * (max+1)
        float4 sb = make_float4(__fadd_rn(bx.x, sh), __fadd_rn(bx.y, sh),
                                __fadd_rn(bx.z, sh), __fadd_rn(bx.w, sh));
        sbox[(size_t)b * M_PAD + i] = sb;
        sarea[(size_t)b * M_PAD + i] = __fmul_rn(__fsub_rn(sb.z, sb.x), __fsub_rn(sb.w, sb.y));
    }
}

// ---------------- 7. suppression bitmask matrix (torchvision-style), only col-blocks >= row-block
__global__ __launch_bounds__(64) void k_sup(const float4* __restrict__ sbox, const float* __restrict__ sarea,
                                            u64* __restrict__ mask) {
    int cb = blockIdx.x, rb = blockIdx.y, b = blockIdx.z;
    if (cb < rb) return;
    __shared__ float4 cbox[64]; __shared__ float carea[64];
    int t = threadIdx.x;
    int j = cb * 64 + t;
    if (j < M_TOT) { cbox[t] = sbox[(size_t)b * M_PAD + j]; carea[t] = sarea[(size_t)b * M_PAD + j]; }
    __syncthreads();
    int i = rb * 64 + t;
    if (i >= M_TOT) return;
    float4 my = sbox[(size_t)b * M_PAD + i];
    float myA = sarea[(size_t)b * M_PAD + i];
    u64 bits = 0;
    int jmax = min(64, M_TOT - cb * 64);
    for (int jj = 0; jj < jmax; ++jj) {
        int jg = cb * 64 + jj;
        if (jg > i) {
            float4 c = cbox[jj];
            float ltx = fmaxf(my.x, c.x), lty = fmaxf(my.y, c.y);
            float rbx = fminf(my.z, c.z), rby = fminf(my.w, c.w);
            float ww = fmaxf(__fsub_rn(rbx, ltx), 0.f), hh = fmaxf(__fsub_rn(rby, lty), 0.f);
            float inter = __fmul_rn(ww, hh);
            // ref FP order: ((area_i + area_j) - inter) + 1e-9
            float den = __fadd_rn(__fsub_rn(__fadd_rn(myA, carea[jj]), inter), 1e-9f);
            float iou = __fdiv_rn(inter, den);
            if (iou > NMS_T) bits |= (1ull << jj);
        }
    }
    mask[((size_t)b * M_PAD + i) * NW + cb] = bits;
}

// ---------------- 8. single-wave blocked greedy NMS scan + output emission
__global__ __launch_bounds__(64) void k_scan(const u64* __restrict__ sortedk, const u64* __restrict__ mask,
                                             const float4* __restrict__ boxes, float* __restrict__ out) {
    int b = blockIdx.x; int lane = threadIdx.x;
    __shared__ u64 removed[NW]; __shared__ u64 keepw[NW];
    // init: removed = invalid (min-size fail => key hi == sortable(-inf)) or padding
    for (int w = 0; w < NW; ++w) {
        int i = w * 64 + lane;
        bool inval = (i >= M_TOT);
        if (!inval) inval = ((u32)(sortedk[(size_t)b * M_PAD + i] >> 32) == INVALID_HI);
        u64 bal = __ballot(inval);
        if (lane == 0) removed[w] = bal;
    }
    __syncthreads();
    int kept_total = 0, nblk = 0;
    for (int blk = 0; blk < NW; ++blk) {
        // diagonal 64x64 tile: lane L holds row (blk*64+L)'s word blk
        u64 diag = mask[((size_t)b * M_PAD + blk * 64 + lane) * NW + blk];
        u64 live = ~removed[blk];
        u64 keep = 0, avail = live;
        while (avail) {                               // uniform across lanes (single wave)
            int i = (int)__ffsll((ull)avail) - 1;
            keep |= (1ull << i);
            avail &= ~(1ull << i);
            u64 r = (u64)__shfl((ull)diag, i, 64);    // uniform-index broadcast
            avail &= ~r;
        }
        if (lane == 0) keepw[blk] = keep;
        kept_total += (int)__popcll((ull)keep);
        nblk = blk + 1;
        if (kept_total >= POSTN) break;               // early exit: output needs only 1000 kept
        int nw2 = NW - (blk + 1);
        if (nw2 > 0 && ((keep >> lane) & 1)) {        // lane-parallel cross-block propagation
            const u64* row = mask + ((size_t)b * M_PAD + blk * 64 + lane) * NW;
            int w = blk + 1 + (lane % nw2);           // staggered start to spread LDS atomics
            for (int t2 = 0; t2 < nw2; ++t2) {
                atomicOr((ull*)&removed[w], (ull)row[w]);
                ++w; if (w >= NW) w = blk + 1;
            }
        }
        __syncthreads();
    }
    __syncthreads();
    // emission: kept boxes in score order, then zero-fill
    int base = 0;
    for (int blk = 0; blk < nblk && base < POSTN; ++blk) {
        u64 kw = keepw[blk];
        if ((kw >> lane) & 1) {
            int rank = base + (int)__popcll((ull)(kw & ((1ull << lane) - 1ull)));
            if (rank < POSTN) {
                int i = blk * 64 + lane;
                u64 key = sortedk[(size_t)b * M_PAD + i];
                u32 p = 0xFFFFFFFFu - (u32)key;
                float sc = __uint_as_float((u32)(key >> 32) & 0x7FFFFFFFu);
                float4 bx = boxes[(size_t)b * M_PAD + p];
                reinterpret_cast<float4*>(out)[b * POSTN + rank] = bx;
                out[16000 + b * POSTN + rank] = sc;
            }
        }
        base += (int)__popcll((ull)kw);
    }
    int emitted = min(base, POSTN);
    for (int r = emitted + lane; r < POSTN; r += 64) {
        reinterpret_cast<float4*>(out)[b * POSTN + r] = make_float4(0.f, 0.f, 0.f, 0.f);
        out[16000 + b * POSTN + r] = 0.0f;
    }
}

// ---------------- workspace layout (bytes, all 16-aligned) ----------------
// hist    @ 0        : 20*65536*4   = 5242880
// binB    @ 5242880  : 80
// cnt     @ 5242960  : 80
// maxbox  @ 5243040  : 16
// cand    @ 5243056  : 20*4096*8   = 655360
// selk    @ 5898416  : 4*4800*8    = 153600
// boxes   @ 6052016  : 4*4800*16   = 307200
// skeyin  @ 6359216  : 153600
// sortedk @ 6512816  : 153600
// sbox    @ 6666416  : 307200
// sarea   @ 6973616  : 76800
// mask    @ 7050416  : 4*4800*75*8 = 11520000
// total 18570416 bytes (~17.7 MB)

extern "C" void kernel_launch(void* const* d_in, const int* in_sizes, int n_in,
                              void* d_out, int out_size, void* d_ws, size_t ws_size,
                              hipStream_t stream) {
    const float* obj     = (const float*)d_in[0];
    const float* deltas  = (const float*)d_in[1];
    const float* anchors = (const float*)d_in[2];
    float* out = (float*)d_out;
    char* ws = (char*)d_ws;
    u32*    hist    = (u32*)   (ws + 0);
    u32*    binB    = (u32*)   (ws + 5242880);
    u32*    cnt     = (u32*)   (ws + 5242960);
    u32*    maxbox  = (u32*)   (ws + 5243040);
    u64*    cand    = (u64*)   (ws + 5243056);
    u64*    selk    = (u64*)   (ws + 5898416);
    float4* boxes   = (float4*)(ws + 6052016);
    u64*    skeyin  = (u64*)   (ws + 6359216);
    u64*    sortedk = (u64*)   (ws + 6512816);
    float4* sbox    = (float4*)(ws + 6666416);
    float*  sarea   = (float*) (ws + 6973616);
    u64*    mask    = (u64*)   (ws + 7050416);

    hipMemsetAsync(d_ws, 0, 5243056, stream);   // hist + binB + cnt + maxbox

    dim3 gA((A_TOTAL + 255) / 256, BATCHN);
    k_hist   <<<gA, 256, 0, stream>>>(obj, hist);
    k_thresh <<<20, 256, 0, stream>>>(hist, binB);
    k_compact<<<gA, 256, 0, stream>>>(obj, binB, cnt, cand);
    k_sortlvl<<<20, 1024, 0, stream>>>(cnt, cand, selk);
    dim3 gD((M_TOT + 255) / 256, BATCHN);
    k_decode <<<gD, 256, 0, stream>>>(selk, deltas, anchors, skeyin, boxes, maxbox);
    k_sortbatch<<<BATCHN, 1024, 0, stream>>>(skeyin, sortedk, boxes, maxbox, sbox, sarea);
    dim3 gS(NW, NW, BATCHN);
    k_sup    <<<gS, 64, 0, stream>>>(sbox, sarea, mask);
    k_scan   <<<BATCHN, 64, 0, stream>>>(sortedk, mask, boxes, out);
}

// Round 8
// 695.585 us; speedup vs baseline: 1.2642x; 1.2642x over previous
//
#include <hip/hip_runtime.h>
#include <stdint.h>

typedef uint32_t u32; typedef uint64_t u64;
typedef unsigned long long ull;

#define A_TOTAL 242991
#define NLVL 5
#define BATCHN 4
#define M_TOT 4741          // 1000*4 + 741
#define M_PAD 4800          // 75 * 64
#define NW 75               // mask words per row (ceil(4741/64))
#define POSTN 1000
#define CAP 4096            // candidate buffer per (batch,level)
#define IMG_W 1216.0f
#define IMG_H 800.0f
#define BBOX_CLIP 4.135166556742356f
#define NMS_T 0.7f
#define MIN_SZ 1e-3f
#define INVALID_HI 0x007FFFFFu   // sortable-u32 of -inf

// LDS bank swizzle for u64 arrays: u64 element i lives in bank pair i%16.
// Bitonic stages with stride>=16 put all 64 lanes on one bank pair (~32-way
// conflict). XOR bits [4:8) into [0:4): involution, bijective, spreads any
// stride-16+ access across all 16 bank pairs. (T2 logic, zero extra LDS.)
#define SW(i) ((i) ^ (((i) >> 4) & 15))

// monotone float->u32 transform (order-preserving; larger float => larger key)
__device__ __forceinline__ u32 fkey(float f) {
    u32 b = __float_as_uint(f);
    return (b & 0x80000000u) ? ~b : (b | 0x80000000u);
}
__device__ __forceinline__ int level_of(int x) {
    return (x < 182400) ? 0 : (x < 228000) ? 1 : (x < 239400) ? 2 : (x < 242250) ? 3 : 4;
}
__device__ __forceinline__ u64 readlane64(u64 v, int lane) {
    u32 lo = (u32)__builtin_amdgcn_readlane((int)(u32)v, lane);
    u32 hi = (u32)__builtin_amdgcn_readlane((int)(u32)(v >> 32), lane);
    return ((u64)hi << 32) | lo;
}
__device__ __forceinline__ u64 uniform64(u64 v) {
    u32 lo = (u32)__builtin_amdgcn_readfirstlane((int)(u32)v);
    u32 hi = (u32)__builtin_amdgcn_readfirstlane((int)(u32)(v >> 32));
    return ((u64)hi << 32) | lo;
}

// ---------------- 1. histogram of top-16 bits of sortable objectness, per (b,level)
__global__ void k_hist(const float* __restrict__ obj, u32* __restrict__ hist) {
    int x = blockIdx.x * blockDim.x + threadIdx.x;
    int b = blockIdx.y;
    if (x >= A_TOTAL) return;
    u32 u = fkey(obj[(size_t)b * A_TOTAL + x]);
    int lvl = level_of(x);
    atomicAdd(&hist[((size_t)(b * NLVL + lvl) << 16) + (u >> 16)], 1u);
}

// ---------------- 2. boundary bin B s.t. count(bin >= B) >= k — fully parallel version
__global__ __launch_bounds__(256) void k_thresh(const u32* __restrict__ hist, u32* __restrict__ binB) {
    int g = blockIdx.x; int lvl = g % NLVL;
    u32 k = (lvl < 4) ? 1000u : 741u;
    const u32* h = hist + ((size_t)g << 16);
    __shared__ u32 ss[256];      // coarse suffix sums (per 256-bin chunk)
    __shared__ u32 sv[256];      // fine suffix sums (within chunk)
    __shared__ int c_star;
    __shared__ u32 above_sh;
    int t = threadIdx.x;
    // coarse: chunk t = bins [t*256, t*256+256), uint4-vectorized
    const uint4* h4 = reinterpret_cast<const uint4*>(h + t * 256);
    u32 sum = 0;
    #pragma unroll 8
    for (int i = 0; i < 64; ++i) { uint4 v = h4[i]; sum += v.x + v.y + v.z + v.w; }
    ss[t] = sum;
    __syncthreads();
    // suffix-scan over chunks (Hillis-Steele)
    for (int d = 1; d < 256; d <<= 1) {
        u32 add = (t + d < 256) ? ss[t + d] : 0u;
        __syncthreads();
        ss[t] += add;
        __syncthreads();
    }
    // ss[c] = count of bins >= c*256. c* = largest c with ss[c] >= k.
    if (ss[t] >= k && (t == 255 || ss[t + 1] < k)) {
        c_star = t;
        above_sh = (t == 255) ? 0u : ss[t + 1];
    }
    __syncthreads();
    int cs = c_star; u32 above = above_sh;
    // fine: suffix within chunk cs
    sv[t] = h[cs * 256 + t];
    __syncthreads();
    for (int d = 1; d < 256; d <<= 1) {
        u32 add = (t + d < 256) ? sv[t + d] : 0u;
        __syncthreads();
        sv[t] += add;
        __syncthreads();
    }
    if (sv[t] + above >= k && (t == 255 || sv[t + 1] + above < k))
        binB[g] = (u32)(cs * 256 + t);
}

// ---------------- 3. compact candidates (bin >= B) with exact 64-bit key (value, ~idx)
__global__ void k_compact(const float* __restrict__ obj, const u32* __restrict__ binB,
                          u32* __restrict__ cnt, u64* __restrict__ cand) {
    int x = blockIdx.x * blockDim.x + threadIdx.x;
    int b = blockIdx.y;
    if (x >= A_TOTAL) return;
    u32 u = fkey(obj[(size_t)b * A_TOTAL + x]);
    int lvl = level_of(x);
    int g = b * NLVL + lvl;
    if ((u >> 16) >= binB[g]) {
        u32 slot = atomicAdd(&cnt[g], 1u);
        if (slot < CAP) cand[(size_t)g * CAP + slot] = ((u64)u << 32) | (u32)(~(u32)x);
    }
}

// ---------------- 4. per-(b,level) exact top-k by bitonic sort (descending); ranks match lax.top_k
// Adaptive size (smallest pow2 >= n) + bank-swizzled LDS.
__global__ __launch_bounds__(1024) void k_sortlvl(const u32* __restrict__ cnt, const u64* __restrict__ cand,
                                                  u64* __restrict__ selk) {
    __shared__ u64 buf[CAP];   // 32 KB
    int g = blockIdx.x; int b = g / NLVL; int lvl = g % NLVL;
    int n = min((int)cnt[g], CAP);
    int ssize = (n <= 1024) ? 1024 : ((n <= 2048) ? 2048 : 4096);
    for (int i = threadIdx.x; i < ssize; i += 1024) buf[SW(i)] = (i < n) ? cand[(size_t)g * CAP + i] : 0ull;
    __syncthreads();
    for (int k = 2; k <= ssize; k <<= 1)
        for (int j = k >> 1; j > 0; j >>= 1) {
            for (int t = threadIdx.x; t < ssize / 2; t += 1024) {
                int i = ((t & ~(j - 1)) << 1) | (t & (j - 1));
                int ix = i | j;
                int si = SW(i), six = SW(ix);
                u64 a = buf[si], c = buf[six];
                bool dirup = ((i & k) != 0);           // flipped => overall descending
                bool sw = dirup ? (a > c) : (a < c);
                if (sw) { buf[si] = c; buf[six] = a; }
            }
            __syncthreads();
        }
    int kk = (lvl < 4) ? 1000 : 741;
    int off = lvl * 1000;
    for (int r = threadIdx.x; r < kk; r += 1024)
        selk[(size_t)b * M_PAD + off + r] = buf[SW(r)];
}

// ---------------- 5. decode + clip + valid + sigmoid, build global sort key, per-batch max
// FP exactness: sigmoid = 1/(1+exp(-x)) matches XLA's LogisticExpander; all mul/add
// pinned un-contracted to match XLA's separate-HLO evaluation (IoU knife-edge at 0.7).
__global__ void k_decode(const u64* __restrict__ selk, const float* __restrict__ deltas,
                         const float* __restrict__ anchors, u64* __restrict__ skeyin,
                         float4* __restrict__ boxes, u32* __restrict__ maxbox) {
    int p = blockIdx.x * blockDim.x + threadIdx.x;
    int b = blockIdx.y;
    float lmax = 0.0f;
    if (p < M_TOT) {
        u64 key = selk[(size_t)b * M_PAD + p];
        u32 u = (u32)(key >> 32);
        u32 gidx = ~(u32)key;
        u32 ob = (u & 0x80000000u) ? (u & 0x7FFFFFFFu) : ~u;   // inverse of fkey
        float o = __uint_as_float(ob);
        float score = 1.0f / (1.0f + expf(-o));
        float4 a4 = reinterpret_cast<const float4*>(anchors)[gidx];
        float4 d4 = reinterpret_cast<const float4*>(deltas)[(size_t)b * A_TOTAL + gidx];
        float w  = __fsub_rn(a4.z, a4.x);
        float h  = __fsub_rn(a4.w, a4.y);
        float cx = __fadd_rn(a4.x, __fmul_rn(0.5f, w));
        float cy = __fadd_rn(a4.y, __fmul_rn(0.5f, h));
        float dw = fminf(d4.z, BBOX_CLIP), dh = fminf(d4.w, BBOX_CLIP);
        float pcx = __fadd_rn(__fmul_rn(d4.x, w), cx);
        float pcy = __fadd_rn(__fmul_rn(d4.y, h), cy);
        float pw = __fmul_rn(expf(dw), w);
        float ph = __fmul_rn(expf(dh), h);
        float x1 = __fsub_rn(pcx, __fmul_rn(0.5f, pw));
        float y1 = __fsub_rn(pcy, __fmul_rn(0.5f, ph));
        float x2 = __fadd_rn(pcx, __fmul_rn(0.5f, pw));
        float y2 = __fadd_rn(pcy, __fmul_rn(0.5f, ph));
        x1 = fminf(fmaxf(x1, 0.f), IMG_W); x2 = fminf(fmaxf(x2, 0.f), IMG_W);
        y1 = fminf(fmaxf(y1, 0.f), IMG_H); y2 = fminf(fmaxf(y2, 0.f), IMG_H);
        bool valid = (__fsub_rn(x2, x1) >= MIN_SZ) && (__fsub_rn(y2, y1) >= MIN_SZ);
        float masked = valid ? score : -INFINITY;
        skeyin[(size_t)b * M_PAD + p] = ((u64)fkey(masked) << 32) | (u32)(0xFFFFFFFFu - (u32)p);
        boxes[(size_t)b * M_PAD + p] = make_float4(x1, y1, x2, y2);
        lmax = fmaxf(fmaxf(x1, y1), fmaxf(x2, y2));
    }
    for (int o = 32; o; o >>= 1) lmax = fmaxf(lmax, __shfl_xor(lmax, o));
    if ((threadIdx.x & 63) == 0) atomicMax((int*)&maxbox[b], __float_as_int(lmax));
}

// ---------------- 6. per-batch global sort (8192 bitonic in LDS, bank-swizzled) + shifted boxes/areas
__global__ __launch_bounds__(1024) void k_sortbatch(const u64* __restrict__ skeyin, u64* __restrict__ sortedk,
                                                    const float4* __restrict__ boxes, const u32* __restrict__ maxbox,
                                                    float4* __restrict__ sbox, float* __restrict__ sarea) {
    __shared__ u64 buf[8192];   // 64 KB
    int b = blockIdx.x;
    for (int i = threadIdx.x; i < 8192; i += 1024)
        buf[SW(i)] = (i < M_TOT) ? skeyin[(size_t)b * M_PAD + i] : 0ull;
    __syncthreads();
    for (int k = 2; k <= 8192; k <<= 1)
        for (int j = k >> 1; j > 0; j >>= 1) {
            for (int t = threadIdx.x; t < 4096; t += 1024) {
                int i = ((t & ~(j - 1)) << 1) | (t & (j - 1));
                int ix = i | j;
                int si = SW(i), six = SW(ix);
                u64 a = buf[si], c = buf[six];
                bool dirup = ((i & k) != 0);
                bool sw = dirup ? (a > c) : (a < c);
                if (sw) { buf[si] = c; buf[six] = a; }
            }
            __syncthreads();
        }
    float shiftbase = __fadd_rn(__uint_as_float(maxbox[b]), 1.0f);   // jnp.max(boxes) + 1.0
    for (int i = threadIdx.x; i < M_TOT; i += 1024) {
        u64 key = buf[SW(i)];
        sortedk[(size_t)b * M_PAD + i] = key;
        u32 p = 0xFFFFFFFFu - (u32)key;
        float4 bx = boxes[(size_t)b * M_PAD + p];
        int lvl = (int)(p / 1000u);
        float sh = __fmul_rn((float)lvl, shiftbase);                 // levels * (max+1)
        float4 sb = make_float4(__fadd_rn(bx.x, sh), __fadd_rn(bx.y, sh),
                                __fadd_rn(bx.z, sh), __fadd_rn(bx.w, sh));
        sbox[(size_t)b * M_PAD + i] = sb;
        sarea[(size_t)b * M_PAD + i] = __fmul_rn(__fsub_rn(sb.z, sb.x), __fsub_rn(sb.w, sb.y));
    }
}

// ---------------- 7. suppression bitmask matrix + compact diag tiles
__global__ __launch_bounds__(64) void k_sup(const float4* __restrict__ sbox, const float* __restrict__ sarea,
                                            u64* __restrict__ mask, u64* __restrict__ diagm) {
    int cb = blockIdx.x, rb = blockIdx.y, b = blockIdx.z;
    if (cb < rb) return;
    __shared__ float4 cbox[64]; __shared__ float carea[64];
    int t = threadIdx.x;
    int j = cb * 64 + t;
    if (j < M_TOT) { cbox[t] = sbox[(size_t)b * M_PAD + j]; carea[t] = sarea[(size_t)b * M_PAD + j]; }
    __syncthreads();
    int i = rb * 64 + t;
    if (i >= M_TOT) return;
    float4 my = sbox[(size_t)b * M_PAD + i];
    float myA = sarea[(size_t)b * M_PAD + i];
    u64 bits = 0;
    int jmax = min(64, M_TOT - cb * 64);
    for (int jj = 0; jj < jmax; ++jj) {
        int jg = cb * 64 + jj;
        if (jg > i) {
            float4 c = cbox[jj];
            float ltx = fmaxf(my.x, c.x), lty = fmaxf(my.y, c.y);
            float rbx = fminf(my.z, c.z), rby = fminf(my.w, c.w);
            float ww = fmaxf(__fsub_rn(rbx, ltx), 0.f), hh = fmaxf(__fsub_rn(rby, lty), 0.f);
            float inter = __fmul_rn(ww, hh);
            float den = __fadd_rn(__fsub_rn(__fadd_rn(myA, carea[jj]), inter), 1e-9f);
            float iou = __fdiv_rn(inter, den);
            if (iou > NMS_T) bits |= (1ull << jj);
        }
    }
    mask[((size_t)b * M_PAD + i) * NW + cb] = bits;
    if (cb == rb) diagm[((size_t)b * NW + rb) * 64 + t] = bits;   // coalesced diag tile
}

// ---------------- 8. blocked greedy NMS scan v2: scalar selection + parallel propagation
__global__ __launch_bounds__(1024) void k_scan(const u64* __restrict__ sortedk, const u64* __restrict__ maskm,
                                               const u64* __restrict__ diagm,
                                               const float4* __restrict__ boxes, float* __restrict__ out) {
    int b = blockIdx.x; int tid = threadIdx.x;
    int wave = tid >> 6, lane = tid & 63;
    __shared__ u64 removed[NW];
    __shared__ u64 keepw[NW];
    __shared__ u64 keep_sh;
    __shared__ int nk_sh;
    __shared__ u32 klist[64];
    // init removed: invalid (min-size fail) or padding rows
    for (int w = wave; w < NW; w += 16) {
        int i = w * 64 + lane;
        bool inval = (i >= M_TOT);
        if (!inval) inval = ((u32)(sortedk[(size_t)b * M_PAD + i] >> 32) == INVALID_HI);
        u64 bal = __ballot(inval);
        if (lane == 0) removed[w] = bal;
    }
    __syncthreads();
    // prefetch diag for block 0 (wave 0 only)
    u64 diag = (tid < 64) ? diagm[((size_t)b * NW + 0) * 64 + tid] : 0ull;
    int kept_total = 0, nblk = 0;
    for (int blk = 0; blk < NW; ++blk) {
        // issue next-block diag load early (hides under this block's work)
        u64 diag_next = 0ull;
        if (tid < 64 && blk + 1 < NW) diag_next = diagm[((size_t)b * NW + blk + 1) * 64 + tid];
        // ---- selection on wave 0, scalar (SGPR) greedy over the 64x64 diag tile
        if (tid < 64) {
            u64 av = uniform64(~removed[blk]);
            u64 keep = 0; int nk = 0;
            while (av) {
                int i = (int)__ffsll((ull)av) - 1;
                keep |= (1ull << i);
                if (tid == 0) klist[nk] = (u32)i;
                ++nk;
                u64 r = readlane64(diag, i);          // keeper's suppression row (uniform)
                av &= ~((1ull << i) | r);
            }
            if (tid == 0) { keep_sh = keep; keepw[blk] = keep; nk_sh = nk; }
        }
        __syncthreads();
        u64 keep = keep_sh; int nk = nk_sh;
        kept_total += (int)__popcll((ull)keep);
        nblk = blk + 1;
        if (kept_total >= POSTN) break;               // uniform early exit
        // ---- propagation: thread = (word-slot wi, part) ; 128 slots x 8 parts
        int wi = tid & 127, part = tid >> 7;
        int w = blk + 1 + wi;
        if (w < NW && nk > 0) {
            const u64* rowbase = maskm + ((size_t)(b * M_PAD + blk * 64)) * NW + w;
            u64 acc = 0;
            #pragma unroll
            for (int s = 0; s < 8; ++s) {             // part handles kept indices part, part+8, ...
                int idx = part + (s << 3);
                u64 v = (idx < nk) ? rowbase[(size_t)klist[idx] * NW] : 0ull;
                acc |= v;
            }
            if (acc) atomicOr((ull*)&removed[w], (ull)acc);
        }
        diag = diag_next;
        __syncthreads();
    }
    __syncthreads();
    // ---- emission on wave 0: kept boxes in score order, then zero-fill
    if (tid < 64) {
        int base = 0;
        for (int blk = 0; blk < nblk && base < POSTN; ++blk) {
            u64 kw = keepw[blk];
            if ((kw >> lane) & 1) {
                int rank = base + (int)__popcll((ull)(kw & ((1ull << lane) - 1ull)));
                if (rank < POSTN) {
                    int i = blk * 64 + lane;
                    u64 key = sortedk[(size_t)b * M_PAD + i];
                    u32 p = 0xFFFFFFFFu - (u32)key;
                    float sc = __uint_as_float((u32)(key >> 32) & 0x7FFFFFFFu);
                    float4 bx = boxes[(size_t)b * M_PAD + p];
                    reinterpret_cast<float4*>(out)[b * POSTN + rank] = bx;
                    out[16000 + b * POSTN + rank] = sc;
                }
            }
            base += (int)__popcll((ull)kw);
        }
        int emitted = min(base, POSTN);
        for (int r = emitted + lane; r < POSTN; r += 64) {
            reinterpret_cast<float4*>(out)[b * POSTN + r] = make_float4(0.f, 0.f, 0.f, 0.f);
            out[16000 + b * POSTN + r] = 0.0f;
        }
    }
}

// ---------------- workspace layout (bytes, all 16-aligned) ----------------
// hist    @ 0        : 20*65536*4   = 5242880
// binB    @ 5242880  : 80
// cnt     @ 5242960  : 80
// maxbox  @ 5243040  : 16
// cand    @ 5243056  : 20*4096*8   = 655360
// selk    @ 5898416  : 4*4800*8    = 153600
// boxes   @ 6052016  : 4*4800*16   = 307200
// skeyin  @ 6359216  : 153600
// sortedk @ 6512816  : 153600
// sbox    @ 6666416  : 307200
// sarea   @ 6973616  : 76800
// mask    @ 7050416  : 4*4800*75*8 = 11520000
// diagm   @ 18570416 : 4*75*64*8   = 153600
// total 18724016 bytes (~17.9 MB)

extern "C" void kernel_launch(void* const* d_in, const int* in_sizes, int n_in,
                              void* d_out, int out_size, void* d_ws, size_t ws_size,
                              hipStream_t stream) {
    const float* obj     = (const float*)d_in[0];
    const float* deltas  = (const float*)d_in[1];
    const float* anchors = (const float*)d_in[2];
    float* out = (float*)d_out;
    char* ws = (char*)d_ws;
    u32*    hist    = (u32*)   (ws + 0);
    u32*    binB    = (u32*)   (ws + 5242880);
    u32*    cnt     = (u32*)   (ws + 5242960);
    u32*    maxbox  = (u32*)   (ws + 5243040);
    u64*    cand    = (u64*)   (ws + 5243056);
    u64*    selk    = (u64*)   (ws + 5898416);
    float4* boxes   = (float4*)(ws + 6052016);
    u64*    skeyin  = (u64*)   (ws + 6359216);
    u64*    sortedk = (u64*)   (ws + 6512816);
    float4* sbox    = (float4*)(ws + 6666416);
    float*  sarea   = (float*) (ws + 6973616);
    u64*    mask    = (u64*)   (ws + 7050416);
    u64*    diagm   = (u64*)   (ws + 18570416);

    hipMemsetAsync(d_ws, 0, 5243056, stream);   // hist + binB + cnt + maxbox

    dim3 gA((A_TOTAL + 255) / 256, BATCHN);
    k_hist   <<<gA, 256, 0, stream>>>(obj, hist);
    k_thresh <<<20, 256, 0, stream>>>(hist, binB);
    k_compact<<<gA, 256, 0, stream>>>(obj, binB, cnt, cand);
    k_sortlvl<<<20, 1024, 0, stream>>>(cnt, cand, selk);
    dim3 gD((M_TOT + 255) / 256, BATCHN);
    k_decode <<<gD, 256, 0, stream>>>(selk, deltas, anchors, skeyin, boxes, maxbox);
    k_sortbatch<<<BATCHN, 1024, 0, stream>>>(skeyin, sortedk, boxes, maxbox, sbox, sarea);
    dim3 gS(NW, NW, BATCHN);
    k_sup    <<<gS, 64, 0, stream>>>(sbox, sarea, mask, diagm);
    k_scan   <<<BATCHN, 1024, 0, stream>>>(sortedk, mask, diagm, boxes, out);
}

// Round 12
// 475.343 us; speedup vs baseline: 1.8499x; 1.4633x over previous
//
#include <hip/hip_runtime.h>
#include <stdint.h>

typedef uint32_t u32; typedef uint64_t u64;
typedef unsigned long long ull;

#define A_TOTAL 242991
#define NLVL 5
#define BATCHN 4
#define M_TOT 4741          // 1000*4 + 741
#define M_PAD 4800          // 75 * 64
#define NW 75               // mask words per row (ceil(4741/64))
#define POSTN 1000
#define CAP 4096            // candidate buffer per (batch,level)
#define CSTRIDE 32          // u32 stride between cnt counters (128 B = own cacheline)
#define IMG_W 1216.0f
#define IMG_H 800.0f
#define BBOX_CLIP 4.135166556742356f
#define NMS_T 0.7f
#define MIN_SZ 1e-3f
#define INVALID_HI 0x007FFFFFu   // sortable-u32 of -inf

// LDS bank swizzle for u64 arrays (bitonic stride>=16 would be ~32-way conflict)
#define SW(i) ((i) ^ (((i) >> 4) & 15))

// monotone float->u32 transform (order-preserving; larger float => larger key)
__device__ __forceinline__ u32 fkey(float f) {
    u32 b = __float_as_uint(f);
    return (b & 0x80000000u) ? ~b : (b | 0x80000000u);
}
__device__ __forceinline__ int level_of(int x) {
    return (x < 182400) ? 0 : (x < 228000) ? 1 : (x < 239400) ? 2 : (x < 242250) ? 3 : 4;
}
__device__ __forceinline__ u64 readlane64(u64 v, int lane) {
    u32 lo = (u32)__builtin_amdgcn_readlane((int)(u32)v, lane);
    u32 hi = (u32)__builtin_amdgcn_readlane((int)(u32)(v >> 32), lane);
    return ((u64)hi << 32) | lo;
}
__device__ __forceinline__ u64 uniform64(u64 v) {
    u32 lo = (u32)__builtin_amdgcn_readfirstlane((int)(u32)v);
    u32 hi = (u32)__builtin_amdgcn_readfirstlane((int)(u32)(v >> 32));
    return ((u64)hi << 32) | lo;
}

// ---------------- 1. histogram of top-16 bits of sortable objectness, per (b,level)
__global__ void k_hist(const float* __restrict__ obj, u32* __restrict__ hist) {
    int x = blockIdx.x * blockDim.x + threadIdx.x;
    int b = blockIdx.y;
    if (x >= A_TOTAL) return;
    u32 u = fkey(obj[(size_t)b * A_TOTAL + x]);
    int lvl = level_of(x);
    atomicAdd(&hist[((size_t)(b * NLVL + lvl) << 16) + (u >> 16)], 1u);
}

// ---------------- 2. boundary bin B s.t. count(bin >= B) >= k — fully parallel version
__global__ __launch_bounds__(256) void k_thresh(const u32* __restrict__ hist, u32* __restrict__ binB) {
    int g = blockIdx.x; int lvl = g % NLVL;
    u32 k = (lvl < 4) ? 1000u : 741u;
    const u32* h = hist + ((size_t)g << 16);
    __shared__ u32 ss[256];      // coarse suffix sums (per 256-bin chunk)
    __shared__ u32 sv[256];      // fine suffix sums (within chunk)
    __shared__ int c_star;
    __shared__ u32 above_sh;
    int t = threadIdx.x;
    // coarse: chunk t = bins [t*256, t*256+256), uint4-vectorized
    const uint4* h4 = reinterpret_cast<const uint4*>(h + t * 256);
    u32 sum = 0;
    #pragma unroll 8
    for (int i = 0; i < 64; ++i) { uint4 v = h4[i]; sum += v.x + v.y + v.z + v.w; }
    ss[t] = sum;
    __syncthreads();
    // suffix-scan over chunks (Hillis-Steele)
    for (int d = 1; d < 256; d <<= 1) {
        u32 add = (t + d < 256) ? ss[t + d] : 0u;
        __syncthreads();
        ss[t] += add;
        __syncthreads();
    }
    // ss[c] = count of bins >= c*256. c* = largest c with ss[c] >= k.
    if (ss[t] >= k && (t == 255 || ss[t + 1] < k)) {
        c_star = t;
        above_sh = (t == 255) ? 0u : ss[t + 1];
    }
    __syncthreads();
    int cs = c_star; u32 above = above_sh;
    // fine: suffix within chunk cs
    sv[t] = h[cs * 256 + t];
    __syncthreads();
    for (int d = 1; d < 256; d <<= 1) {
        u32 add = (t + d < 256) ? sv[t + d] : 0u;
        __syncthreads();
        sv[t] += add;
        __syncthreads();
    }
    if (sv[t] + above >= k && (t == 255 || sv[t + 1] + above < k))
        binB[g] = (u32)(cs * 256 + t);
}

// ---------------- 3. compact candidates v3: LDS-staged thresholds + block-aggregated slot
// reservation. Fixes Round-8 pathology: binB shared a cacheline with the cnt atomics →
// every wave's binB read was a coherence miss on a continuously-dirtied line (211 µs).
// Now: one binB line-read per block into LDS; one global atomicAdd per (block, level).
// Candidate order within cand changes — irrelevant (k_sortlvl fully sorts, exact keys).
__global__ __launch_bounds__(256) void k_compact(const float* __restrict__ obj, const u32* __restrict__ binB,
                                                 u32* __restrict__ cnt, u64* __restrict__ cand) {
    __shared__ u32 sB[NLVL];
    __shared__ u32 lcnt[NLVL];
    __shared__ u32 lbase[NLVL];
    int t = threadIdx.x;
    int b = blockIdx.y;
    if (t < NLVL) { sB[t] = binB[b * NLVL + t]; lcnt[t] = 0; }
    __syncthreads();
    int x = blockIdx.x * 256 + t;
    bool pass = false; int lvl = 0; u32 u = 0, lslot = 0;
    if (x < A_TOTAL) {
        u = fkey(obj[(size_t)b * A_TOTAL + x]);
        lvl = level_of(x);
        if ((u >> 16) >= sB[lvl]) { pass = true; lslot = atomicAdd(&lcnt[lvl], 1u); }
    }
    __syncthreads();
    if (t < NLVL && lcnt[t] != 0) lbase[t] = atomicAdd(&cnt[(b * NLVL + t) * CSTRIDE], lcnt[t]);
    __syncthreads();
    if (pass) {
        u32 slot = lbase[lvl] + lslot;
        if (slot < CAP) cand[(size_t)(b * NLVL + lvl) * CAP + slot] = ((u64)u << 32) | (u32)(~(u32)x);
    }
}

// ---------------- 4. per-(b,level) exact top-k by bitonic sort (descending); ranks match lax.top_k
// Adaptive size (smallest pow2 >= n) + bank-swizzled LDS.
__global__ __launch_bounds__(1024) void k_sortlvl(const u32* __restrict__ cnt, const u64* __restrict__ cand,
                                                  u64* __restrict__ selk) {
    __shared__ u64 buf[CAP];   // 32 KB
    int g = blockIdx.x; int b = g / NLVL; int lvl = g % NLVL;
    int n = min((int)cnt[g * CSTRIDE], CAP);
    int ssize = (n <= 1024) ? 1024 : ((n <= 2048) ? 2048 : 4096);
    for (int i = threadIdx.x; i < ssize; i += 1024) buf[SW(i)] = (i < n) ? cand[(size_t)g * CAP + i] : 0ull;
    __syncthreads();
    for (int k = 2; k <= ssize; k <<= 1)
        for (int j = k >> 1; j > 0; j >>= 1) {
            for (int t = threadIdx.x; t < ssize / 2; t += 1024) {
                int i = ((t & ~(j - 1)) << 1) | (t & (j - 1));
                int ix = i | j;
                int si = SW(i), six = SW(ix);
                u64 a = buf[si], c = buf[six];
                bool dirup = ((i & k) != 0);           // flipped => overall descending
                bool sw = dirup ? (a > c) : (a < c);
                if (sw) { buf[si] = c; buf[six] = a; }
            }
            __syncthreads();
        }
    int kk = (lvl < 4) ? 1000 : 741;
    int off = lvl * 1000;
    for (int r = threadIdx.x; r < kk; r += 1024)
        selk[(size_t)b * M_PAD + off + r] = buf[SW(r)];
}

// ---------------- 5. decode + clip + valid + sigmoid, build global sort key, per-batch max
// FP exactness: sigmoid = 1/(1+exp(-x)) matches XLA's LogisticExpander; all mul/add
// pinned un-contracted to match XLA's separate-HLO evaluation (IoU knife-edge at 0.7).
__global__ void k_decode(const u64* __restrict__ selk, const float* __restrict__ deltas,
                         const float* __restrict__ anchors, u64* __restrict__ skeyin,
                         float4* __restrict__ boxes, u32* __restrict__ maxbox) {
    int p = blockIdx.x * blockDim.x + threadIdx.x;
    int b = blockIdx.y;
    float lmax = 0.0f;
    if (p < M_TOT) {
        u64 key = selk[(size_t)b * M_PAD + p];
        u32 u = (u32)(key >> 32);
        u32 gidx = ~(u32)key;
        u32 ob = (u & 0x80000000u) ? (u & 0x7FFFFFFFu) : ~u;   // inverse of fkey
        float o = __uint_as_float(ob);
        float score = 1.0f / (1.0f + expf(-o));
        float4 a4 = reinterpret_cast<const float4*>(anchors)[gidx];
        float4 d4 = reinterpret_cast<const float4*>(deltas)[(size_t)b * A_TOTAL + gidx];
        float w  = __fsub_rn(a4.z, a4.x);
        float h  = __fsub_rn(a4.w, a4.y);
        float cx = __fadd_rn(a4.x, __fmul_rn(0.5f, w));
        float cy = __fadd_rn(a4.y, __fmul_rn(0.5f, h));
        float dw = fminf(d4.z, BBOX_CLIP), dh = fminf(d4.w, BBOX_CLIP);
        float pcx = __fadd_rn(__fmul_rn(d4.x, w), cx);
        float pcy = __fadd_rn(__fmul_rn(d4.y, h), cy);
        float pw = __fmul_rn(expf(dw), w);
        float ph = __fmul_rn(expf(dh), h);
        float x1 = __fsub_rn(pcx, __fmul_rn(0.5f, pw));
        float y1 = __fsub_rn(pcy, __fmul_rn(0.5f, ph));
        float x2 = __fadd_rn(pcx, __fmul_rn(0.5f, pw));
        float y2 = __fadd_rn(pcy, __fmul_rn(0.5f, ph));
        x1 = fminf(fmaxf(x1, 0.f), IMG_W); x2 = fminf(fmaxf(x2, 0.f), IMG_W);
        y1 = fminf(fmaxf(y1, 0.f), IMG_H); y2 = fminf(fmaxf(y2, 0.f), IMG_H);
        bool valid = (__fsub_rn(x2, x1) >= MIN_SZ) && (__fsub_rn(y2, y1) >= MIN_SZ);
        float masked = valid ? score : -INFINITY;
        skeyin[(size_t)b * M_PAD + p] = ((u64)fkey(masked) << 32) | (u32)(0xFFFFFFFFu - (u32)p);
        boxes[(size_t)b * M_PAD + p] = make_float4(x1, y1, x2, y2);
        lmax = fmaxf(fmaxf(x1, y1), fmaxf(x2, y2));
    }
    for (int o = 32; o; o >>= 1) lmax = fmaxf(lmax, __shfl_xor(lmax, o));
    if ((threadIdx.x & 63) == 0) atomicMax((int*)&maxbox[b], __float_as_int(lmax));
}

// ---------------- 6. per-batch global sort (8192 bitonic in LDS, bank-swizzled) + shifted boxes/areas
__global__ __launch_bounds__(1024) void k_sortbatch(const u64* __restrict__ skeyin, u64* __restrict__ sortedk,
                                                    const float4* __restrict__ boxes, const u32* __restrict__ maxbox,
                                                    float4* __restrict__ sbox, float* __restrict__ sarea) {
    __shared__ u64 buf[8192];   // 64 KB
    int b = blockIdx.x;
    for (int i = threadIdx.x; i < 8192; i += 1024)
        buf[SW(i)] = (i < M_TOT) ? skeyin[(size_t)b * M_PAD + i] : 0ull;
    __syncthreads();
    for (int k = 2; k <= 8192; k <<= 1)
        for (int j = k >> 1; j > 0; j >>= 1) {
            for (int t = threadIdx.x; t < 4096; t += 1024) {
                int i = ((t & ~(j - 1)) << 1) | (t & (j - 1));
                int ix = i | j;
                int si = SW(i), six = SW(ix);
                u64 a = buf[si], c = buf[six];
                bool dirup = ((i & k) != 0);
                bool sw = dirup ? (a > c) : (a < c);
                if (sw) { buf[si] = c; buf[six] = a; }
            }
            __syncthreads();
        }
    float shiftbase = __fadd_rn(__uint_as_float(maxbox[b]), 1.0f);   // jnp.max(boxes) + 1.0
    for (int i = threadIdx.x; i < M_TOT; i += 1024) {
        u64 key = buf[SW(i)];
        sortedk[(size_t)b * M_PAD + i] = key;
        u32 p = 0xFFFFFFFFu - (u32)key;
        float4 bx = boxes[(size_t)b * M_PAD + p];
        int lvl = (int)(p / 1000u);
        float sh = __fmul_rn((float)lvl, shiftbase);                 // levels * (max+1)
        float4 sb = make_float4(__fadd_rn(bx.x, sh), __fadd_rn(bx.y, sh),
                                __fadd_rn(bx.z, sh), __fadd_rn(bx.w, sh));
        sbox[(size_t)b * M_PAD + i] = sb;
        sarea[(size_t)b * M_PAD + i] = __fmul_rn(__fsub_rn(sb.z, sb.x), __fsub_rn(sb.w, sb.y));
    }
}

// ---------------- 7. suppression bitmask matrix + compact diag tiles
__global__ __launch_bounds__(64) void k_sup(const float4* __restrict__ sbox, const float* __restrict__ sarea,
                                            u64* __restrict__ mask, u64* __restrict__ diagm) {
    int cb = blockIdx.x, rb = blockIdx.y, b = blockIdx.z;
    if (cb < rb) return;
    __shared__ float4 cbox[64]; __shared__ float carea[64];
    int t = threadIdx.x;
    int j = cb * 64 + t;
    if (j < M_TOT) { cbox[t] = sbox[(size_t)b * M_PAD + j]; carea[t] = sarea[(size_t)b * M_PAD + j]; }
    __syncthreads();
    int i = rb * 64 + t;
    if (i >= M_TOT) return;
    float4 my = sbox[(size_t)b * M_PAD + i];
    float myA = sarea[(size_t)b * M_PAD + i];
    u64 bits = 0;
    int jmax = min(64, M_TOT - cb * 64);
    for (int jj = 0; jj < jmax; ++jj) {
        int jg = cb * 64 + jj;
        if (jg > i) {
            float4 c = cbox[jj];
            float ltx = fmaxf(my.x, c.x), lty = fmaxf(my.y, c.y);
            float rbx = fminf(my.z, c.z), rby = fminf(my.w, c.w);
            float ww = fmaxf(__fsub_rn(rbx, ltx), 0.f), hh = fmaxf(__fsub_rn(rby, lty), 0.f);
            float inter = __fmul_rn(ww, hh);
            float den = __fadd_rn(__fsub_rn(__fadd_rn(myA, carea[jj]), inter), 1e-9f);
            float iou = __fdiv_rn(inter, den);
            if (iou > NMS_T) bits |= (1ull << jj);
        }
    }
    mask[((size_t)b * M_PAD + i) * NW + cb] = bits;
    if (cb == rb) diagm[((size_t)b * NW + rb) * 64 + t] = bits;   // coalesced diag tile
}

// ---------------- 8. blocked greedy NMS scan v2: scalar selection + parallel propagation
__global__ __launch_bounds__(1024) void k_scan(const u64* __restrict__ sortedk, const u64* __restrict__ maskm,
                                               const u64* __restrict__ diagm,
                                               const float4* __restrict__ boxes, float* __restrict__ out) {
    int b = blockIdx.x; int tid = threadIdx.x;
    int wave = tid >> 6, lane = tid & 63;
    __shared__ u64 removed[NW];
    __shared__ u64 keepw[NW];
    __shared__ u64 keep_sh;
    __shared__ int nk_sh;
    __shared__ u32 klist[64];
    // init removed: invalid (min-size fail) or padding rows
    for (int w = wave; w < NW; w += 16) {
        int i = w * 64 + lane;
        bool inval = (i >= M_TOT);
        if (!inval) inval = ((u32)(sortedk[(size_t)b * M_PAD + i] >> 32) == INVALID_HI);
        u64 bal = __ballot(inval);
        if (lane == 0) removed[w] = bal;
    }
    __syncthreads();
    // prefetch diag for block 0 (wave 0 only)
    u64 diag = (tid < 64) ? diagm[((size_t)b * NW + 0) * 64 + tid] : 0ull;
    int kept_total = 0, nblk = 0;
    for (int blk = 0; blk < NW; ++blk) {
        // issue next-block diag load early (hides under this block's work)
        u64 diag_next = 0ull;
        if (tid < 64 && blk + 1 < NW) diag_next = diagm[((size_t)b * NW + blk + 1) * 64 + tid];
        // ---- selection on wave 0, scalar (SGPR) greedy over the 64x64 diag tile
        if (tid < 64) {
            u64 av = uniform64(~removed[blk]);
            u64 keep = 0; int nk = 0;
            while (av) {
                int i = (int)__ffsll((ull)av) - 1;
                keep |= (1ull << i);
                if (tid == 0) klist[nk] = (u32)i;
                ++nk;
                u64 r = readlane64(diag, i);          // keeper's suppression row (uniform)
                av &= ~((1ull << i) | r);
            }
            if (tid == 0) { keep_sh = keep; keepw[blk] = keep; nk_sh = nk; }
        }
        __syncthreads();
        u64 keep = keep_sh; int nk = nk_sh;
        kept_total += (int)__popcll((ull)keep);
        nblk = blk + 1;
        if (kept_total >= POSTN) break;               // uniform early exit
        // ---- propagation: thread = (word-slot wi, part) ; 128 slots x 8 parts
        int wi = tid & 127, part = tid >> 7;
        int w = blk + 1 + wi;
        if (w < NW && nk > 0) {
            const u64* rowbase = maskm + ((size_t)(b * M_PAD + blk * 64)) * NW + w;
            u64 acc = 0;
            #pragma unroll
            for (int s = 0; s < 8; ++s) {             // part handles kept indices part, part+8, ...
                int idx = part + (s << 3);
                u64 v = (idx < nk) ? rowbase[(size_t)klist[idx] * NW] : 0ull;
                acc |= v;
            }
            if (acc) atomicOr((ull*)&removed[w], (ull)acc);
        }
        diag = diag_next;
        __syncthreads();
    }
    __syncthreads();
    // ---- emission on wave 0: kept boxes in score order, then zero-fill
    if (tid < 64) {
        int base = 0;
        for (int blk = 0; blk < nblk && base < POSTN; ++blk) {
            u64 kw = keepw[blk];
            if ((kw >> lane) & 1) {
                int rank = base + (int)__popcll((ull)(kw & ((1ull << lane) - 1ull)));
                if (rank < POSTN) {
                    int i = blk * 64 + lane;
                    u64 key = sortedk[(size_t)b * M_PAD + i];
                    u32 p = 0xFFFFFFFFu - (u32)key;
                    float sc = __uint_as_float((u32)(key >> 32) & 0x7FFFFFFFu);
                    float4 bx = boxes[(size_t)b * M_PAD + p];
                    reinterpret_cast<float4*>(out)[b * POSTN + rank] = bx;
                    out[16000 + b * POSTN + rank] = sc;
                }
            }
            base += (int)__popcll((ull)kw);
        }
        int emitted = min(base, POSTN);
        for (int r = emitted + lane; r < POSTN; r += 64) {
            reinterpret_cast<float4*>(out)[b * POSTN + r] = make_float4(0.f, 0.f, 0.f, 0.f);
            out[16000 + b * POSTN + r] = 0.0f;
        }
    }
}

// ---------------- workspace layout (bytes; small atomic arrays cacheline-isolated) ----
// hist    @ 0        : 20*65536*4   = 5242880
// binB    @ 5242880  : 80   (own 256-B region; read-only after k_thresh)
// cnt     @ 5243136  : 20*128 B = 2560 (one counter per 128-B line, CSTRIDE=32 u32)
// maxbox  @ 5245696  : 16   (own 256-B region)
// cand    @ 5245952  : 20*4096*8   = 655360
// selk    @ 5901312  : 4*4800*8    = 153600
// boxes   @ 6054912  : 4*4800*16   = 307200
// skeyin  @ 6362112  : 153600
// sortedk @ 6515712  : 153600
// sbox    @ 6669312  : 307200
// sarea   @ 6976512  : 76800
// mask    @ 7053312  : 4*4800*75*8 = 11520000
// diagm   @ 18573312 : 4*75*64*8   = 153600
// total 18726912 bytes (~17.9 MB)

extern "C" void kernel_launch(void* const* d_in, const int* in_sizes, int n_in,
                              void* d_out, int out_size, void* d_ws, size_t ws_size,
                              hipStream_t stream) {
    const float* obj     = (const float*)d_in[0];
    const float* deltas  = (const float*)d_in[1];
    const float* anchors = (const float*)d_in[2];
    float* out = (float*)d_out;
    char* ws = (char*)d_ws;
    u32*    hist    = (u32*)   (ws + 0);
    u32*    binB    = (u32*)   (ws + 5242880);
    u32*    cnt     = (u32*)   (ws + 5243136);
    u32*    maxbox  = (u32*)   (ws + 5245696);
    u64*    cand    = (u64*)   (ws + 5245952);
    u64*    selk    = (u64*)   (ws + 5901312);
    float4* boxes   = (float4*)(ws + 6054912);
    u64*    skeyin  = (u64*)   (ws + 6362112);
    u64*    sortedk = (u64*)   (ws + 6515712);
    float4* sbox    = (float4*)(ws + 6669312);
    float*  sarea   = (float*) (ws + 6976512);
    u64*    mask    = (u64*)   (ws + 7053312);
    u64*    diagm   = (u64*)   (ws + 18573312);

    hipMemsetAsync(d_ws, 0, 5245952, stream);   // hist + binB + cnt + maxbox

    dim3 gA((A_TOTAL + 255) / 256, BATCHN);
    k_hist   <<<gA, 256, 0, stream>>>(obj, hist);
    k_thresh <<<20, 256, 0, stream>>>(hist, binB);
    k_compact<<<gA, 256, 0, stream>>>(obj, binB, cnt, cand);
    k_sortlvl<<<20, 1024, 0, stream>>>(cnt, cand, selk);
    dim3 gD((M_TOT + 255) / 256, BATCHN);
    k_decode <<<gD, 256, 0, stream>>>(selk, deltas, anchors, skeyin, boxes, maxbox);
    k_sortbatch<<<BATCHN, 1024, 0, stream>>>(skeyin, sortedk, boxes, maxbox, sbox, sarea);
    dim3 gS(NW, NW, BATCHN);
    k_sup    <<<gS, 64, 0, stream>>>(sbox, sarea, mask, diagm);
    k_scan   <<<BATCHN, 1024, 0, stream>>>(sortedk, mask, diagm, boxes, out);
}